// Round 3
// baseline (91.148 us; speedup 1.0000x reference)
//
#include <hip/hip_runtime.h>

// AdjacencyAttention: B=4096, N=64, D=256, fp32 in/out. Two-kernel split:
//   K1 (dots): streaming GEMV over x at HBM peak -> lhs/rhs stashed in out region
//   K2 (attn): tanh(outer+bs) -> bf16 hi/lo split -> Vs@t via MFMA -> softmax

typedef float f32x4 __attribute__((ext_vector_type(4)));
typedef __bf16 bf16x8 __attribute__((ext_vector_type(8)));

// ---------------------------------------------------------------------------
// K1: lhs[b][n] = (x[b,n,:]·W2)*W1, rhs[b][n] = x[b,n,:]·W3
// Stored at out[b*4096 + n] and out[b*4096 + 64 + n] (K2 reads then overwrites).
// Each wave: 2 groups of 16 rows; lane-quad (4 lanes) per row; 16 chunk iters.
__global__ __launch_bounds__(256, 8) void adjatt_dots(
    const float* __restrict__ x,   // (B,64,256)
    const float* __restrict__ W1,  // (1,)
    const float* __restrict__ W2,  // (256,1)
    const float* __restrict__ W3,  // (256,)
    float* __restrict__ out,       // (B,64,64) - first 128 floats/batch used as stash
    int R)                         // total rows = B*64
{
    const int lane = threadIdx.x & 63;
    const int w    = threadIdx.x >> 6;
    const int gw   = blockIdx.x * 4 + w;   // global wave index
    const int q    = lane & 3;             // quad position within row
    const int rsub = lane >> 2;            // row within 16-row group
    const float W1v = W1[0];

    #pragma unroll
    for (int g = 0; g < 2; ++g) {
        const int r = gw * 32 + g * 16 + rsub;
        if (r >= R) break;
        const float* xr = x + (size_t)r * 256 + q * 4;
        float d2 = 0.f, d3 = 0.f;
        #pragma unroll
        for (int c = 0; c < 16; ++c) {
            f32x4 xv = *(const f32x4*)(xr + c * 16);
            f32x4 w2 = *(const f32x4*)(W2 + c * 16 + q * 4);
            f32x4 w3 = *(const f32x4*)(W3 + c * 16 + q * 4);
            d2 = fmaf(xv[0], w2[0], d2); d2 = fmaf(xv[1], w2[1], d2);
            d2 = fmaf(xv[2], w2[2], d2); d2 = fmaf(xv[3], w2[3], d2);
            d3 = fmaf(xv[0], w3[0], d3); d3 = fmaf(xv[1], w3[1], d3);
            d3 = fmaf(xv[2], w3[2], d3); d3 = fmaf(xv[3], w3[3], d3);
        }
        d2 += __shfl_xor(d2, 1); d2 += __shfl_xor(d2, 2);
        d3 += __shfl_xor(d3, 1); d3 += __shfl_xor(d3, 2);
        if (q == 0) {
            const int b = r >> 6, n = r & 63;
            out[(size_t)b * 4096 + n]      = d2 * W1v;
            out[(size_t)b * 4096 + 64 + n] = d3;
        }
    }
}

// ---------------------------------------------------------------------------
// K2: per batch: t = tanh(outer(lhs,rhs)+bs) (bf16 hi/lo), s = Vs@t via MFMA,
//     softmax over flattened 4096, store.
__global__ __launch_bounds__(256, 4) void adjatt_attn(
    const float* __restrict__ bs,  // (1,64,64)
    const float* __restrict__ Vs,  // (64,64)
    float* __restrict__ out)       // (B,64,64); [0..127] of each batch = lhs/rhs stash
{
    __shared__ __align__(16) unsigned char tT[16384]; // [0,8K): hi bf16 [n][j] swz; [8K,16K): lo
    __shared__ __align__(16) float lhs[64];
    __shared__ __align__(16) float rhs[64];
    __shared__ float redm[4], reds[4];

    const int tid  = threadIdx.x;
    const int b    = blockIdx.x;
    const int lane = tid & 63;
    const int w    = tid >> 6;

    // ---- Load precomputed lhs/rhs (written by K1) ----
    if (tid < 128) {
        float v = out[(size_t)b * 4096 + tid];
        if (tid < 64) lhs[tid] = v; else rhs[tid - 64] = v;
    }

    // ---- A fragments (Vs rows 16w..16w+15) direct from global, hi/lo split ----
    // A-frag layout (16x16x32): lane l holds A[l&15][8*(l>>4) + e], e=0..7 (k-contig)
    bf16x8 Ah[2], Al[2];
    {
        const int row = 16 * w + (lane & 15);
        #pragma unroll
        for (int s = 0; s < 2; ++s) {
            const float* vp = Vs + row * 64 + 32 * s + 8 * (lane >> 4);
            f32x4 f0 = *(const f32x4*)vp;
            f32x4 f1 = *(const f32x4*)(vp + 4);
            #pragma unroll
            for (int e = 0; e < 4; ++e) {
                __bf16 h0 = (__bf16)f0[e];
                Ah[s][e] = h0;
                Al[s][e] = (__bf16)(f0[e] - (float)h0);
                __bf16 h1 = (__bf16)f1[e];
                Ah[s][e + 4] = h1;
                Al[s][e + 4] = (__bf16)(f1[e] - (float)h1);
            }
        }
    }
    __syncthreads();

    // ---- Phase 2: t[j][n] = tanh(lhs[j]*rhs[n] + bs[j][n]) -> tT[n][j] bf16 hi/lo ----
    {
        const int n  = lane;        // column
        const int j0 = 16 * w;      // this wave covers j0..j0+15
        const float rv = rhs[n];
        f32x4 lh[4];
        #pragma unroll
        for (int c = 0; c < 4; ++c) lh[c] = *(const f32x4*)&lhs[j0 + 4 * c];
        bf16x8 hi[2], lo[2];
        #pragma unroll
        for (int jj = 0; jj < 16; ++jj) {
            float z  = fmaf(lh[jj >> 2][jj & 3], rv, bs[(j0 + jj) * 64 + n]);
            float e2 = __expf(2.f * z);
            float th = 1.f - __fdividef(2.f, e2 + 1.f);  // tanh, saturates correctly
            __bf16 h = (__bf16)th;
            hi[jj >> 3][jj & 7] = h;
            lo[jj >> 3][jj & 7] = (__bf16)(th - (float)h);
        }
        #pragma unroll
        for (int c = 0; c < 2; ++c) {
            const int off = (n * 128 + (j0 + 8 * c) * 2) ^ ((n & 7) << 4);
            *(bf16x8*)(tT + off)        = hi[c];
            *(bf16x8*)(tT + 8192 + off) = lo[c];
        }
    }
    __syncthreads();

    // ---- Phase 3: s(rows 16w..16w+15, all 64 cols) = Vs @ t via MFMA ----
    // B-frag: lane l holds t[32s + 8*(l>>4) + e][16nt + (l&15)]  (k-contig in tT[n][j])
    f32x4 acc[4];
    #pragma unroll
    for (int nt = 0; nt < 4; ++nt) acc[nt] = (f32x4){0.f, 0.f, 0.f, 0.f};
    #pragma unroll
    for (int nt = 0; nt < 4; ++nt) {
        const int n = 16 * nt + (lane & 15);
        #pragma unroll
        for (int s = 0; s < 2; ++s) {
            const int off = (n * 128 + 64 * s + 16 * (lane >> 4)) ^ ((n & 7) << 4);
            bf16x8 Bh = *(const bf16x8*)(tT + off);
            bf16x8 Bl = *(const bf16x8*)(tT + 8192 + off);
            acc[nt] = __builtin_amdgcn_mfma_f32_16x16x32_bf16(Ah[s], Bh, acc[nt], 0, 0, 0);
            acc[nt] = __builtin_amdgcn_mfma_f32_16x16x32_bf16(Al[s], Bh, acc[nt], 0, 0, 0);
            acc[nt] = __builtin_amdgcn_mfma_f32_16x16x32_bf16(Ah[s], Bl, acc[nt], 0, 0, 0);
        }
    }

    // ---- Phase 4: softmax over all 4096 scores of this batch ----
    float m = acc[0][0];
    #pragma unroll
    for (int nt = 0; nt < 4; ++nt)
        #pragma unroll
        for (int e = 0; e < 4; ++e) m = fmaxf(m, acc[nt][e]);
    #pragma unroll
    for (int off = 1; off < 64; off <<= 1) m = fmaxf(m, __shfl_xor(m, off));
    if (lane == 0) redm[w] = m;
    __syncthreads();
    const float M = fmaxf(fmaxf(redm[0], redm[1]), fmaxf(redm[2], redm[3]));

    float ssum = 0.f;
    #pragma unroll
    for (int nt = 0; nt < 4; ++nt)
        #pragma unroll
        for (int e = 0; e < 4; ++e) {
            acc[nt][e] = __expf(acc[nt][e] - M);
            ssum += acc[nt][e];
        }
    #pragma unroll
    for (int off = 1; off < 64; off <<= 1) ssum += __shfl_xor(ssum, off);
    if (lane == 0) reds[w] = ssum;
    __syncthreads();
    const float inv = __fdividef(1.f, reds[0] + reds[1] + reds[2] + reds[3]);

    // ---- Store: D layout row = 16w + 4*(l>>4) + e, col = 16nt + (l&15) ----
    float* ob = out + (size_t)b * 4096;
    const int rbase = 16 * w + 4 * (lane >> 4);
    const int cbase = lane & 15;
    #pragma unroll
    for (int nt = 0; nt < 4; ++nt) {
        const int col = 16 * nt + cbase;
        #pragma unroll
        for (int e = 0; e < 4; ++e) {
            ob[(rbase + e) * 64 + col] = acc[nt][e] * inv;
        }
    }
}

extern "C" void kernel_launch(void* const* d_in, const int* in_sizes, int n_in,
                              void* d_out, int out_size, void* d_ws, size_t ws_size,
                              hipStream_t stream) {
    const float* x  = (const float*)d_in[0];
    const float* W1 = (const float*)d_in[1];
    const float* W2 = (const float*)d_in[2];
    const float* W3 = (const float*)d_in[3];
    const float* bs = (const float*)d_in[4];
    const float* Vs = (const float*)d_in[5];
    float* out = (float*)d_out;

    const int B = in_sizes[0] / (64 * 256);
    const int R = B * 64;                       // total rows
    const int grid1 = (R + 127) / 128;          // 128 rows per block (4 waves x 32)

    adjatt_dots<<<dim3(grid1), dim3(256), 0, stream>>>(x, W1, W2, W3, out, R);
    adjatt_attn<<<dim3(B), dim3(256), 0, stream>>>(bs, Vs, out);
}

// Round 4
// 74.536 us; speedup vs baseline: 1.2229x; 1.2229x over previous
//
#include <hip/hip_runtime.h>

// AdjacencyAttention: B=4096, N=64, D=256, fp32 in/out. Fused, 1 block/batch,
// 6 blocks/CU target. P1: lhs/rhs dots (4 thr/row, weights from L1).
// P2: t = tanh(outer+bs) -> bf16 hi/lo, [n][j] XOR-swizzled LDS.
// P3: s^T = t^T @ Vs^T via mfma_16x16x32_bf16 (operand-swapped, 3-product split).
// P4: block softmax over 4096, float4 stores.

typedef float f32x4 __attribute__((ext_vector_type(4)));
typedef __bf16 bf16x8 __attribute__((ext_vector_type(8)));

__global__ __launch_bounds__(256, 6) void adjatt_kernel(
    const float* __restrict__ x,   // (B,64,256)
    const float* __restrict__ W1,  // (1,)
    const float* __restrict__ W2,  // (256,1)
    const float* __restrict__ W3,  // (256,)
    const float* __restrict__ bs,  // (1,64,64)
    const float* __restrict__ Vs,  // (64,64)
    float* __restrict__ out)       // (B,64,64)
{
    __shared__ __align__(16) unsigned char tT[16384]; // [0,8K): hi bf16 [n][j] swz; [8K,16K): lo
    __shared__ __align__(16) float lhs[64];
    __shared__ __align__(16) float rhs[64];
    __shared__ float redm[4], reds[4];

    const int tid  = threadIdx.x;
    const int b    = blockIdx.x;
    const int lane = tid & 63;
    const int w    = tid >> 6;
    const float W1v = W1[0];

    // ---- Phase 1: lhs[r] = (x[r,:]·W2)*W1 ; rhs[r] = x[r,:]·W3 (4 thr/row) ----
    {
        const int r = tid >> 2;          // row 0..63
        const int q = tid & 3;           // quad slot: lane-quads read 64B contiguous
        const float* xr  = x + (size_t)b * 16384 + r * 256 + q * 4;
        const float* w2p = W2 + q * 4;   // L1-hot (2KB total weights)
        const float* w3p = W3 + q * 4;
        float d2 = 0.f, d3 = 0.f;
        #pragma unroll 4
        for (int c = 0; c < 16; ++c) {
            f32x4 xv = *(const f32x4*)(xr + c * 16);
            f32x4 w2 = *(const f32x4*)(w2p + c * 16);
            f32x4 w3 = *(const f32x4*)(w3p + c * 16);
            d2 = fmaf(xv[0], w2[0], d2); d2 = fmaf(xv[1], w2[1], d2);
            d2 = fmaf(xv[2], w2[2], d2); d2 = fmaf(xv[3], w2[3], d2);
            d3 = fmaf(xv[0], w3[0], d3); d3 = fmaf(xv[1], w3[1], d3);
            d3 = fmaf(xv[2], w3[2], d3); d3 = fmaf(xv[3], w3[3], d3);
        }
        d2 += __shfl_xor(d2, 1); d2 += __shfl_xor(d2, 2);
        d3 += __shfl_xor(d3, 1); d3 += __shfl_xor(d3, 2);
        if (q == 0) { lhs[r] = d2 * W1v; rhs[r] = d3; }
    }
    __syncthreads();

    // ---- Vs fragments (rows 16w..16w+15), hi/lo split; used as the B operand ----
    // frag layout: lane l holds M[l&15][8*(l>>4)+e], e=0..7 (k-contiguous)
    bf16x8 Vh[2], Vl[2];
    {
        const int row = 16 * w + (lane & 15);
        #pragma unroll
        for (int s = 0; s < 2; ++s) {
            const float* vp = Vs + row * 64 + 32 * s + 8 * (lane >> 4);
            f32x4 f0 = *(const f32x4*)vp;
            f32x4 f1 = *(const f32x4*)(vp + 4);
            #pragma unroll
            for (int e = 0; e < 4; ++e) {
                __bf16 h0 = (__bf16)f0[e];
                Vh[s][e] = h0;
                Vl[s][e] = (__bf16)(f0[e] - (float)h0);
                __bf16 h1 = (__bf16)f1[e];
                Vh[s][e + 4] = h1;
                Vl[s][e + 4] = (__bf16)(f1[e] - (float)h1);
            }
        }
    }

    // ---- Phase 2: t[j][n] = tanh(lhs[j]*rhs[n] + bs[j][n]) -> tT[n][j] hi/lo ----
    {
        const int n  = lane;        // t column
        const int j0 = 16 * w;      // this wave covers rows j0..j0+15
        const float rv = rhs[n];
        f32x4 lh[4];
        #pragma unroll
        for (int c = 0; c < 4; ++c) lh[c] = *(const f32x4*)&lhs[j0 + 4 * c];
        bf16x8 hi[2], lo[2];
        #pragma unroll
        for (int jj = 0; jj < 16; ++jj) {
            float z  = fmaf(lh[jj >> 2][jj & 3], rv, bs[(j0 + jj) * 64 + n]);
            float e2 = __expf(2.f * z);
            float th = 1.f - __fdividef(2.f, e2 + 1.f);  // tanh, saturates at +/-1
            __bf16 h = (__bf16)th;
            hi[jj >> 3][jj & 7] = h;
            lo[jj >> 3][jj & 7] = (__bf16)(th - (float)h);
        }
        #pragma unroll
        for (int c = 0; c < 2; ++c) {
            const int off = (n * 128 + (j0 + 8 * c) * 2) ^ ((n & 7) << 4);
            *(bf16x8*)(tT + off)        = hi[c];
            *(bf16x8*)(tT + 8192 + off) = lo[c];
        }
    }
    __syncthreads();

    // ---- Phase 3: s^T = t^T @ Vs^T (operand-swapped MFMA) ----
    // acc[ct]: s-rows 16w..16w+15 (from Vs frag, N dim), s-cols 16ct..16ct+15 (M dim)
    f32x4 acc[4];
    #pragma unroll
    for (int ct = 0; ct < 4; ++ct) acc[ct] = (f32x4){0.f, 0.f, 0.f, 0.f};
    #pragma unroll
    for (int ct = 0; ct < 4; ++ct) {
        const int n = 16 * ct + (lane & 15);   // t column read by this lane
        #pragma unroll
        for (int sk = 0; sk < 2; ++sk) {
            const int off = (n * 128 + 64 * sk + 16 * (lane >> 4)) ^ ((n & 7) << 4);
            bf16x8 Th = *(const bf16x8*)(tT + off);
            bf16x8 Tl = *(const bf16x8*)(tT + 8192 + off);
            acc[ct] = __builtin_amdgcn_mfma_f32_16x16x32_bf16(Th, Vh[sk], acc[ct], 0, 0, 0);
            acc[ct] = __builtin_amdgcn_mfma_f32_16x16x32_bf16(Tl, Vh[sk], acc[ct], 0, 0, 0);
            acc[ct] = __builtin_amdgcn_mfma_f32_16x16x32_bf16(Th, Vl[sk], acc[ct], 0, 0, 0);
        }
    }

    // ---- Phase 4: softmax over all 4096 scores of this batch ----
    float m = acc[0][0];
    #pragma unroll
    for (int ct = 0; ct < 4; ++ct)
        #pragma unroll
        for (int e = 0; e < 4; ++e) m = fmaxf(m, acc[ct][e]);
    #pragma unroll
    for (int off = 1; off < 64; off <<= 1) m = fmaxf(m, __shfl_xor(m, off));
    if (lane == 0) redm[w] = m;
    __syncthreads();
    const float M = fmaxf(fmaxf(redm[0], redm[1]), fmaxf(redm[2], redm[3]));

    float ssum = 0.f;
    #pragma unroll
    for (int ct = 0; ct < 4; ++ct)
        #pragma unroll
        for (int e = 0; e < 4; ++e) {
            acc[ct][e] = __expf(acc[ct][e] - M);
            ssum += acc[ct][e];
        }
    #pragma unroll
    for (int off = 1; off < 64; off <<= 1) ssum += __shfl_xor(ssum, off);
    if (lane == 0) reds[w] = ssum;
    __syncthreads();
    const float inv = __fdividef(1.f, reds[0] + reds[1] + reds[2] + reds[3]);

    // ---- Store: lane holds s[16w+(l&15)][16ct + 4*(l>>4) .. +3] -> float4 ----
    float* ob = out + (size_t)b * 4096 + (16 * w + (lane & 15)) * 64 + 4 * (lane >> 4);
    #pragma unroll
    for (int ct = 0; ct < 4; ++ct) {
        f32x4 v = {acc[ct][0] * inv, acc[ct][1] * inv, acc[ct][2] * inv, acc[ct][3] * inv};
        *(f32x4*)(ob + 16 * ct) = v;
    }
}

extern "C" void kernel_launch(void* const* d_in, const int* in_sizes, int n_in,
                              void* d_out, int out_size, void* d_ws, size_t ws_size,
                              hipStream_t stream) {
    const float* x  = (const float*)d_in[0];
    const float* W1 = (const float*)d_in[1];
    const float* W2 = (const float*)d_in[2];
    const float* W3 = (const float*)d_in[3];
    const float* bs = (const float*)d_in[4];
    const float* Vs = (const float*)d_in[5];
    float* out = (float*)d_out;

    const int B = in_sizes[0] / (64 * 256);
    adjatt_kernel<<<dim3(B), dim3(256), 0, stream>>>(x, W1, W2, W3, bs, Vs, out);
}